// Round 8
// baseline (208.035 us; speedup 1.0000x reference)
//
#include <hip/hip_runtime.h>

// EdgeConv2d: B=4, C=128, N=4096, K=16, COUT=128, GROUPS=4
//
// Factorized: Y[b][n][o] per-node (268 MFLOP), then per-edge gather+relu+mean.
// R8: k2 gather de-serialized — edge indices loaded once per node via
// wave-uniform loads + readfirstlane (SGPR-resident), gather loop unroll 8
// with SGPR-base addressing => 12-16 L2 loads in flight (was ~6 behind a
// shfl->readfirstlane->load chain). Diagnostic 3x amplification RETAINED
// for a clean same-amplification A/B vs R7's 68us. Output bit-identical.

#define BB   4
#define CC   128
#define NN   4096
#define KK   16
#define CO   128

// ---------------------------------------------------------------------------
// Kernel 1 (unchanged, verified passing): Y[b][n][o] = sum_c W[o][c]*x[b][c][n]
// ---------------------------------------------------------------------------
__global__ __launch_bounds__(512) void precompute_y(
    const float* __restrict__ x,   // [B,128,N]
    const float* __restrict__ w,   // [128,64]
    float* __restrict__ Y)         // [B,N,128] node-major
{
    const int lane = threadIdx.x & 63;
    const int wv = __builtin_amdgcn_readfirstlane((int)(threadIdx.x >> 6)); // 0..7

    const int bid  = blockIdx.x;
    const int work = (bid & 7) * ((int)gridDim.x >> 3) + (bid >> 3);

    const int gnode = work * 64 + lane;     // global node id = b*N + n
    const int b = gnode >> 12;              // N = 4096
    const int n = gnode & (NN - 1);

    const int obase = wv * 16;
    const int cbase = ((wv >> 1) & 1) * 64;

    const float* xp = x + ((size_t)(b * CC + cbase)) * NN + n;
    float xr[64];
#pragma unroll
    for (int c = 0; c < 64; ++c) xr[c] = xp[(size_t)c * NN];

    const float* wp = w + obase * 64;
    float buf[16];
#pragma unroll
    for (int oi = 0; oi < 16; ++oi) {
        float acc = 0.f;
#pragma unroll
        for (int c = 0; c < 64; ++c) acc = fmaf(wp[oi * 64 + c], xr[c], acc);
        buf[oi] = acc;
    }

    float* yp = Y + (size_t)gnode * CO + obase;
#pragma unroll
    for (int q = 0; q < 4; ++q) {
        float4 v = make_float4(buf[4*q], buf[4*q+1], buf[4*q+2], buf[4*q+3]);
        *(float4*)(yp + 4 * q) = v;
    }
}

// ---------------------------------------------------------------------------
// Kernel 2 v3: SGPR edge indices + deep-pipelined gather.
// 1024 blocks x 512 threads; 16 nodes/block, lane owns o={2l,2l+1}.
// ---------------------------------------------------------------------------
#define NPB 16
__global__ __launch_bounds__(512, 8) void edge_gather(
    const int*   __restrict__ ei,    // [2,B,N,K] int32
    const float* __restrict__ Y,     // [B,N,128]
    const float* __restrict__ bias,  // [128]
    float* __restrict__ out)         // [B,128,N]
{
    __shared__ float tile[NPB][132];

    const int lane = threadIdx.x & 63;
    const int wv   = __builtin_amdgcn_readfirstlane((int)(threadIdx.x >> 6)); // 0..7

    const int bid  = blockIdx.x;
    const int work = (bid & 7) * ((int)gridDim.x >> 3) + (bid >> 3);

    const int node0 = work * NPB;
    const int b     = node0 >> 12;
    const float* Yb = Y + (size_t)b * NN * CO;

    const float2 b2 = *(const float2*)(bias + 2 * lane);
    const bool hi = (lane >= 32);

    const int* i0p = ei;                          // edge_index[0] (j)
    const int* i1p = ei + (size_t)BB * NN * KK;   // edge_index[1] (i)

#pragma unroll
    for (int s = 0; s < 2; ++s) {
        const int t = wv + 8 * s;            // node slot (wave-uniform)
        const int gnode = node0 + t;
        const int ibase = gnode * KK;        // wave-uniform index base

        // load all 16 index pairs once; force SGPR residency
        int i1s[KK], jjs[KK];
#pragma unroll
        for (int k = 0; k < KK; ++k) {
            i1s[k] = __builtin_amdgcn_readfirstlane(i1p[ibase + k]);
            jjs[k] = __builtin_amdgcn_readfirstlane(i0p[ibase + k]);
        }

        // ---- real pass (output-identical) ----
        float accx = 0.f, accy = 0.f;
#pragma unroll 8
        for (int k = 0; k < KK; ++k) {
            const float2 yi = *(const float2*)(Yb + (size_t)i1s[k] * CO + 2 * lane);
            float2 yj = make_float2(0.f, 0.f);
            if (hi) yj = *(const float2*)(Yb + (size_t)jjs[k] * CO + 2 * lane);
            const float vx = hi ? (yj.x - yi.x) : yi.x;
            const float vy = hi ? (yj.y - yi.y) : yi.y;
            accx += fmaxf(vx + b2.x, 0.f);
            accy += fmaxf(vy + b2.y, 0.f);
        }
        *(float2*)&tile[t][2 * lane] =
            make_float2(accx * (1.f / KK), accy * (1.f / KK));

        // ---- diagnostic passes x3 (same structure, kept live, no store) ----
        float dx = 0.f, dy = 0.f;
#pragma unroll 1
        for (int r = 0; r < 3; ++r) {
            asm volatile("" ::: "memory");   // force reloads (no CSE across r)
#pragma unroll 8
            for (int k = 0; k < KK; ++k) {
                const float2 yi = *(const float2*)(Yb + (size_t)i1s[k] * CO + 2 * lane);
                dx += yi.x; dy += yi.y;
                if (hi) {
                    const float2 yj = *(const float2*)(Yb + (size_t)jjs[k] * CO + 2 * lane);
                    dx += yj.x; dy += yj.y;
                }
            }
        }
        asm volatile("" :: "v"(dx), "v"(dy));  // keep-alive, no DCE (rule #17)
    }
    __syncthreads();

    const int n0   = node0 & (NN - 1);
    const int nloc = lane & 15;
    const int ob   = wv * 16 + (lane >> 4) * 4;
    const float4 v = *(const float4*)&tile[nloc][ob];
    float* op = out + ((size_t)(b * CO + ob)) * NN + n0 + nloc;
    op[0]              = v.x;
    op[(size_t)NN]     = v.y;
    op[2 * (size_t)NN] = v.z;
    op[3 * (size_t)NN] = v.w;
}

// ---------------------------------------------------------------------------
// Fallback (only if workspace < 8MB): direct per-(b,n) compute.
// ---------------------------------------------------------------------------
__global__ __launch_bounds__(128) void edgeconv_fallback(
    const int*   __restrict__ ei,
    const float* __restrict__ x,
    const float* __restrict__ w,
    const float* __restrict__ bias,
    float* __restrict__ out)
{
    const int bn = blockIdx.x;
    const int b  = bn >> 12;
    const int n  = bn & (NN - 1);
    const int o  = threadIdx.x;
    const int g  = o >> 5;
    const int cbase = (g & 1) * 64;
    const bool useJ = (g >= 2);

    const float* xb = x + (size_t)b * CC * NN;
    const int* i0p = ei;
    const int* i1p = ei + (size_t)BB * NN * KK;

    float wr[64];
#pragma unroll
    for (int c = 0; c < 64; ++c) wr[c] = w[o * 64 + c];

    float acc = 0.f;
    for (int k = 0; k < KK; ++k) {
        const int i1 = i1p[(size_t)bn * KK + k];
        const int j  = i0p[(size_t)bn * KK + k];
        float dot = 0.f;
#pragma unroll
        for (int c = 0; c < 64; ++c) {
            const float xi = xb[(size_t)(cbase + c) * NN + i1];
            const float f  = useJ ? (xb[(size_t)(cbase + c) * NN + j] - xi) : xi;
            dot = fmaf(wr[c], f, dot);
        }
        acc += fmaxf(dot + bias[o], 0.f);
    }
    out[((size_t)(b * CO + o)) * NN + n] = acc * (1.f / KK);
}

extern "C" void kernel_launch(void* const* d_in, const int* in_sizes, int n_in,
                              void* d_out, int out_size, void* d_ws, size_t ws_size,
                              hipStream_t stream) {
    const float* x    = (const float*)d_in[0];
    const int*   ei   = (const int*)d_in[1];
    const float* w    = (const float*)d_in[2];
    const float* bias = (const float*)d_in[3];
    float* out = (float*)d_out;

    const size_t need = (size_t)BB * NN * CO * sizeof(float); // 8 MB for Y
    if (ws_size >= need) {
        float* Y = (float*)d_ws;
        precompute_y<<<dim3(BB * NN / 64), dim3(512), 0, stream>>>(x, w, Y);
        edge_gather<<<dim3(BB * NN / NPB), dim3(512), 0, stream>>>(ei, Y, bias, out);
    } else {
        edgeconv_fallback<<<dim3(BB * NN), dim3(128), 0, stream>>>(ei, x, w, bias, out);
    }
}

// Round 10
// 103.067 us; speedup vs baseline: 2.0184x; 2.0184x over previous
//
#include <hip/hip_runtime.h>

// EdgeConv2d: B=4, C=128, N=4096, K=16, COUT=128, GROUPS=4
//
// Factorized: Y[b][n][o] per-node (268 MFLOP, 16x less than per-edge matvec),
// then per-edge gather+relu+mean from node-major Y (512B rows, ~99% L2-served
// per R7 counters: FETCH 9MB for ~800MB of requests).
// R9: production (R7 diag probe removed). Edge indices fully unrolled into
// SGPRs (R8's partial-unroll runtime-indexed arrays went to scratch — rule
// #20; WRITE_SIZE 8->74MB was scratch traffic). launch_bounds(512,4) for
// spill-free 16-deep load ILP.

#define BB   4
#define CC   128
#define NN   4096
#define KK   16
#define CO   128

// ---------------------------------------------------------------------------
// Kernel 1 (unchanged, verified): Y[b][n][o] = sum_c W[o][c]*x[b][c][n]
// 256 blocks x 512 threads. lane = node (coalesced x), wave = 16 o-channels.
// ---------------------------------------------------------------------------
__global__ __launch_bounds__(512) void precompute_y(
    const float* __restrict__ x,   // [B,128,N]
    const float* __restrict__ w,   // [128,64]
    float* __restrict__ Y)         // [B,N,128] node-major
{
    const int lane = threadIdx.x & 63;
    const int wv = __builtin_amdgcn_readfirstlane((int)(threadIdx.x >> 6)); // 0..7

    const int bid  = blockIdx.x;
    const int work = (bid & 7) * ((int)gridDim.x >> 3) + (bid >> 3);

    const int gnode = work * 64 + lane;     // global node id = b*N + n
    const int b = gnode >> 12;              // N = 4096
    const int n = gnode & (NN - 1);

    const int obase = wv * 16;
    const int cbase = ((wv >> 1) & 1) * 64;

    const float* xp = x + ((size_t)(b * CC + cbase)) * NN + n;
    float xr[64];
#pragma unroll
    for (int c = 0; c < 64; ++c) xr[c] = xp[(size_t)c * NN];

    const float* wp = w + obase * 64;
    float buf[16];
#pragma unroll
    for (int oi = 0; oi < 16; ++oi) {
        float acc = 0.f;
#pragma unroll
        for (int c = 0; c < 64; ++c) acc = fmaf(wp[oi * 64 + c], xr[c], acc);
        buf[oi] = acc;
    }

    float* yp = Y + (size_t)gnode * CO + obase;
#pragma unroll
    for (int q = 0; q < 4; ++q) {
        float4 v = make_float4(buf[4*q], buf[4*q+1], buf[4*q+2], buf[4*q+3]);
        *(float4*)(yp + 4 * q) = v;
    }
}

// ---------------------------------------------------------------------------
// Kernel 2 v4: SGPR edge indices (FULL unroll -> compile-time indexing, no
// scratch), 16-deep gather ILP. 1024 blocks x 512 threads; 16 nodes/block,
// lane owns o={2l,2l+1}; hi half-wave additionally reads Yj.
// ---------------------------------------------------------------------------
#define NPB 16
__global__ __launch_bounds__(512, 4) void edge_gather(
    const int*   __restrict__ ei,    // [2,B,N,K] int32
    const float* __restrict__ Y,     // [B,N,128]
    const float* __restrict__ bias,  // [128]
    float* __restrict__ out)         // [B,128,N]
{
    __shared__ float tile[NPB][132];

    const int lane = threadIdx.x & 63;
    const int wv   = __builtin_amdgcn_readfirstlane((int)(threadIdx.x >> 6)); // 0..7

    // chunked XCD swizzle (1024 % 8 == 0 -> bijective), aligned with kernel 1
    const int bid  = blockIdx.x;
    const int work = (bid & 7) * ((int)gridDim.x >> 3) + (bid >> 3);

    const int node0 = work * NPB;
    const int b     = node0 >> 12;
    const float* Yb = Y + (size_t)b * NN * CO;

    const float2 b2 = *(const float2*)(bias + 2 * lane);
    const bool hi = (lane >= 32);

    const int* i0p = ei;                          // edge_index[0] (j)
    const int* i1p = ei + (size_t)BB * NN * KK;   // edge_index[1] (i)

#pragma unroll
    for (int s = 0; s < 2; ++s) {
        const int t = wv + 8 * s;            // node slot (wave-uniform)
        const int gnode = node0 + t;
        const int ibase = gnode * KK;        // wave-uniform index base

        // all 16 index pairs -> SGPRs. FULL unroll: compile-time k only
        // (partial unroll would runtime-index the arrays -> scratch, R8).
        int i1s[KK], jjs[KK];
#pragma unroll
        for (int k = 0; k < KK; ++k) {
            i1s[k] = __builtin_amdgcn_readfirstlane(i1p[ibase + k]);
            jjs[k] = __builtin_amdgcn_readfirstlane(i0p[ibase + k]);
        }

        float accx = 0.f, accy = 0.f;
#pragma unroll
        for (int k = 0; k < KK; ++k) {
            const float2 yi = *(const float2*)(Yb + (size_t)i1s[k] * CO + 2 * lane);
            float2 yj = make_float2(0.f, 0.f);
            if (hi) yj = *(const float2*)(Yb + (size_t)jjs[k] * CO + 2 * lane);
            const float vx = hi ? (yj.x - yi.x) : yi.x;
            const float vy = hi ? (yj.y - yi.y) : yi.y;
            accx += fmaxf(vx + b2.x, 0.f);
            accy += fmaxf(vy + b2.y, 0.f);
        }
        *(float2*)&tile[t][2 * lane] =
            make_float2(accx * (1.f / KK), accy * (1.f / KK));
    }
    __syncthreads();

    // write-out: 16-lane groups span n -> 64B-coalesced dword stores
    const int n0   = node0 & (NN - 1);
    const int nloc = lane & 15;
    const int ob   = wv * 16 + (lane >> 4) * 4;
    const float4 v = *(const float4*)&tile[nloc][ob];
    float* op = out + ((size_t)(b * CO + ob)) * NN + n0 + nloc;
    op[0]              = v.x;
    op[(size_t)NN]     = v.y;
    op[2 * (size_t)NN] = v.z;
    op[3 * (size_t)NN] = v.w;
}

// ---------------------------------------------------------------------------
// Fallback (only if workspace < 8MB): direct per-(b,n) compute.
// ---------------------------------------------------------------------------
__global__ __launch_bounds__(128) void edgeconv_fallback(
    const int*   __restrict__ ei,
    const float* __restrict__ x,
    const float* __restrict__ w,
    const float* __restrict__ bias,
    float* __restrict__ out)
{
    const int bn = blockIdx.x;
    const int b  = bn >> 12;
    const int n  = bn & (NN - 1);
    const int o  = threadIdx.x;
    const int g  = o >> 5;
    const int cbase = (g & 1) * 64;
    const bool useJ = (g >= 2);

    const float* xb = x + (size_t)b * CC * NN;
    const int* i0p = ei;
    const int* i1p = ei + (size_t)BB * NN * KK;

    float wr[64];
#pragma unroll
    for (int c = 0; c < 64; ++c) wr[c] = w[o * 64 + c];

    float acc = 0.f;
    for (int k = 0; k < KK; ++k) {
        const int i1 = i1p[(size_t)bn * KK + k];
        const int j  = i0p[(size_t)bn * KK + k];
        float dot = 0.f;
#pragma unroll
        for (int c = 0; c < 64; ++c) {
            const float xi = xb[(size_t)(cbase + c) * NN + i1];
            const float f  = useJ ? (xb[(size_t)(cbase + c) * NN + j] - xi) : xi;
            dot = fmaf(wr[c], f, dot);
        }
        acc += fmaxf(dot + bias[o], 0.f);
    }
    out[((size_t)(b * CO + o)) * NN + n] = acc * (1.f / KK);
}

extern "C" void kernel_launch(void* const* d_in, const int* in_sizes, int n_in,
                              void* d_out, int out_size, void* d_ws, size_t ws_size,
                              hipStream_t stream) {
    const float* x    = (const float*)d_in[0];
    const int*   ei   = (const int*)d_in[1];
    const float* w    = (const float*)d_in[2];
    const float* bias = (const float*)d_in[3];
    float* out = (float*)d_out;

    const size_t need = (size_t)BB * NN * CO * sizeof(float); // 8 MB for Y
    if (ws_size >= need) {
        float* Y = (float*)d_ws;
        precompute_y<<<dim3(BB * NN / 64), dim3(512), 0, stream>>>(x, w, Y);
        edge_gather<<<dim3(BB * NN / NPB), dim3(512), 0, stream>>>(ei, Y, bias, out);
    } else {
        edgeconv_fallback<<<dim3(BB * NN), dim3(128), 0, stream>>>(ei, x, w, bias, out);
    }
}